// Round 5
// baseline (17410.231 us; speedup 1.0000x reference)
//
#include <hip/hip_runtime.h>

// Problem constants
#define NROWS 16384      // 8 * (8*16*16)
#define NE 8192
#define NCH 32           // k-chunks per row for screening
#define CHK 256          // k's per chunk
#define OUT_LOSS 4194304
#define OUT_IDX  4194305

#define U_MARGIN  2.0e-5f   // candidate margin in u = -dot units (proof: 1.55e-5 needed)
#define CH_MARGIN 2.5e-5f   // chunk-qualify margin

// ---------------- S1[n] = np.sum(zf*zf, axis=1) bit-exact emulation ----------------
// numpy pairwise_sum over 256 fp32: 128+128; each 128-block: 8 accumulators
// r[j] += w[8t+j], tree ((r0+r1)+(r2+r3))+((r4+r5)+(r6+r7)); S1 = blk0+blk1.
__global__ void k_s1(const float* __restrict__ Z, float* __restrict__ S1) {
#pragma clang fp contract(off)
    const int n = blockIdx.x * 256 + threadIdx.x;
    const int b = n >> 11, m = n & 2047;
    const float* zp = Z + b * 524288 + m;   // element c at zp[c*2048]
    float blk[2];
#pragma unroll
    for (int h = 0; h < 2; ++h) {
        float r[8];
#pragma unroll
        for (int j = 0; j < 8; ++j) {
            float z = zp[(h * 128 + j) * 2048];
            float w = z * z;
            asm("" : "+v"(w));
            r[j] = w;
        }
        for (int t2 = 1; t2 < 16; ++t2) {
#pragma unroll
            for (int j = 0; j < 8; ++j) {
                float z = zp[(h * 128 + t2 * 8 + j) * 2048];
                float w = z * z;
                asm("" : "+v"(w));
                r[j] += w;
            }
        }
        float s01 = r[0] + r[1], s23 = r[2] + r[3];
        float s45 = r[4] + r[5], s67 = r[6] + r[7];
        blk[h] = (s01 + s23) + (s45 + s67);
    }
    S1[n] = blk[0] + blk[1];
}

// ---------------- fast fp32 screen: partmin[chunk][n] = min_k(-z.e) ----------------
// grid 1024: rb = bid>>2 (64 rows each), ks = bid&3 (2048 k's = 8 chunks).
// thread: j = t&3 owns c in [64j, 64j+64) as 64 pinned VGPRs; row n = rb*64 + t>>2.
// Free association: fmaf + tree + shfl combine. Screen score u = -dot (monotone
// surrogate for d_np up to the row-constant S1 and |err| <= ~1e-8 + S2-absorption).
__launch_bounds__(256, 3)
__global__ void k_screen(const float* __restrict__ Z, const float* __restrict__ E,
                         float* __restrict__ partmin) {
    const int t = threadIdx.x;
    const int j = t & 3;
    const int rb = blockIdx.x >> 2;
    const int ks = blockIdx.x & 3;
    const int n = rb * 64 + (t >> 2);
    const int b = n >> 11, m = n & 2047;

    const float* zp = Z + b * 524288 + m;
    float zr[64];
#pragma unroll
    for (int u = 0; u < 64; ++u) zr[u] = zp[(64 * j + u) * 2048];
#pragma unroll
    for (int u = 0; u < 64; ++u) { asm("" : "+v"(zr[u])); }

    const int k0 = ks * 2048;
    for (int ch = 0; ch < 8; ++ch) {
        float cmin = INFINITY;
        for (int kk = 0; kk < CHK; ++kk) {
            const int k = k0 + ch * CHK + kk;
            const float4* ep = reinterpret_cast<const float4*>(E + k * 256 + 64 * j);
            float ax = 0.f, ay = 0.f, az = 0.f, aw = 0.f;
#pragma unroll
            for (int u = 0; u < 16; ++u) {
                float4 e4 = ep[u];
                ax = fmaf(zr[4 * u + 0], e4.x, ax);
                ay = fmaf(zr[4 * u + 1], e4.y, ay);
                az = fmaf(zr[4 * u + 2], e4.z, az);
                aw = fmaf(zr[4 * u + 3], e4.w, aw);
            }
            float a = (ax + ay) + (az + aw);
            a += __shfl_xor(a, 1);
            a += __shfl_xor(a, 2);
            cmin = fminf(cmin, -a);
        }
        if (j == 0) partmin[(ks * 8 + ch) * NROWS + n] = cmin;
    }
}

// ---------------- rowmin[n] = min over chunks ----------------
__global__ void k_rowmin(const float* __restrict__ partmin, float* __restrict__ rowmin) {
    const int n = blockIdx.x * 256 + threadIdx.x;
    float mn = INFINITY;
#pragma unroll
    for (int ch = 0; ch < NCH; ++ch) mn = fminf(mn, partmin[ch * NROWS + n]);
    rowmin[n] = mn;
}

// ---------------- rescue: exact np-emulation on candidates only ----------------
// one wave per row (4 waves/block). For qualifying chunks, each lane screens 4
// strided k's; lanes whose u <= rowmin+U_MARGIN emulate the exact SSE 4-chain
// P_np in-lane (z via LDS float4 broadcast, e via global float4), d = fl(S1-2P),
// then wave-reduces lexicographic min of packed (d,k).
__global__ void k_rescue(const float* __restrict__ Z, const float* __restrict__ E,
                         const float* __restrict__ S1, const float* __restrict__ partmin,
                         const float* __restrict__ rowmin, int* __restrict__ idxv,
                         float* __restrict__ out) {
#pragma clang fp contract(off)
    __shared__ __align__(16) float zsm[4][256];
    const int t = threadIdx.x;
    const int r = t >> 6;            // wave id = row within block
    const int lane = t & 63;
    const int n = blockIdx.x * 4 + r;
    const int b = n >> 11, m = n & 2047;

    // stage z row into LDS (exact fp32 copies)
#pragma unroll
    for (int i = 0; i < 4; ++i)
        zsm[r][lane + 64 * i] = Z[b * 524288 + (lane + 64 * i) * 2048 + m];
    __syncthreads();

    const float4* zf4 = reinterpret_cast<const float4*>(zsm[r]);
    const float rowm = rowmin[n];
    const float s1v = S1[n];

    unsigned long long best = 0xFFFFFFFFFFFFFFFFull;

    float pm = (lane < NCH) ? partmin[lane * NROWS + n] : INFINITY;
    unsigned long long qm = __ballot(pm <= rowm + CH_MARGIN);
    while (qm) {
        const int ch = __ffsll(qm) - 1;
        qm &= qm - 1;
        const int c0 = ch * CHK;
#pragma unroll 1
        for (int s = 0; s < 4; ++s) {
            const int k = c0 + s * 64 + lane;
            // fast screen dot (free association)
            const float4* ef = reinterpret_cast<const float4*>(E + k * 256);
            float ax = 0.f, ay = 0.f, az = 0.f, aw = 0.f;
#pragma unroll
            for (int u = 0; u < 64; ++u) {
                float4 e4 = ef[u];
                float4 zz = zf4[u];
                ax = fmaf(zz.x, e4.x, ax);
                ay = fmaf(zz.y, e4.y, ay);
                az = fmaf(zz.z, e4.z, az);
                aw = fmaf(zz.w, e4.w, aw);
            }
            const float uk = -((ax + ay) + (az + aw));
            if (uk <= rowm + U_MARGIN) {
                // exact np SSE 4-chain emulation (sequential, no fma, no reassoc)
                float a0 = 0.f, a1 = 0.f, a2 = 0.f, a3 = 0.f;
#pragma unroll
                for (int u = 0; u < 64; ++u) {
                    float4 e4 = ef[u];
                    float4 zz = zf4[u];
                    float p0 = zz.x * e4.x; asm("" : "+v"(p0)); a0 += p0;
                    float p1 = zz.y * e4.y; asm("" : "+v"(p1)); a1 += p1;
                    float p2 = zz.z * e4.z; asm("" : "+v"(p2)); a2 += p2;
                    float p3 = zz.w * e4.w; asm("" : "+v"(p3)); a3 += p3;
                }
                float t1 = a0 + a1;
                float t2 = a2 + a3;
                float Pn = t1 + t2;                 // fl(fl(A0+A1)+fl(A2+A3))
                float d = s1v - 2.0f * Pn;          // fl(S1 - 2P), S2 absorbed
                unsigned long long pk =
                    ((unsigned long long)__float_as_uint(d) << 32) | (unsigned)k;
                if (pk < best) best = pk;
            }
        }
    }

    // wave-reduce lexicographic min of (d, k)
#pragma unroll
    for (int o = 32; o; o >>= 1) {
        unsigned lo = (unsigned)(best & 0xFFFFFFFFull);
        unsigned hi = (unsigned)(best >> 32);
        unsigned olo = __shfl_xor(lo, o);
        unsigned ohi = __shfl_xor(hi, o);
        unsigned long long ob = ((unsigned long long)ohi << 32) | olo;
        if (ob < best) best = ob;
    }
    if (lane == 0) {
        const int bi = (int)(best & 0xFFFFFFFFull);
        idxv[n] = bi;
        out[OUT_IDX + n] = (float)bi;
    }
}

// ---------------- fp64 ||z - e_idx||^2 per row (for the loss) ----------------
__global__ void k_dmin(const float* __restrict__ Z, const float* __restrict__ E,
                       const int* __restrict__ idxv, double* __restrict__ dmin) {
    const int n = blockIdx.x * 4 + (threadIdx.x >> 6);
    const int lane = threadIdx.x & 63;
    const int b = n >> 11, m = n & 2047;
    const int kk = idxv[n];
    const float4 e4 = reinterpret_cast<const float4*>(E + kk * 256)[lane];
    const float* zp = Z + b * 524288 + m;
    double d0 = (double)zp[(4 * lane + 0) * 2048] - (double)e4.x;
    double d1 = (double)zp[(4 * lane + 1) * 2048] - (double)e4.y;
    double d2 = (double)zp[(4 * lane + 2) * 2048] - (double)e4.z;
    double d3 = (double)zp[(4 * lane + 3) * 2048] - (double)e4.w;
    double d = d0 * d0 + d1 * d1 + d2 * d2 + d3 * d3;
    for (int o = 32; o; o >>= 1) d += __shfl_xor(d, o);
    if (lane == 0) dmin[n] = d;
}

// ---------------- gather z_q with LDS transpose ----------------
__global__ void k_gather(const float* __restrict__ emb, const int* __restrict__ idxv,
                         float* __restrict__ out) {
    __shared__ float tile[32][33];
    __shared__ int kidx[32];
    const int blk = blockIdx.x;
    const int ct = blk & 7;
    const int mt = (blk >> 3) & 63;
    const int b = blk >> 9;
    const int t = threadIdx.x, tr = t >> 5, tc = t & 31;

    if (t < 32) kidx[t] = idxv[b * 2048 + mt * 32 + t];
    __syncthreads();
#pragma unroll
    for (int rr = 0; rr < 4; ++rr) {
        int row = tr + rr * 8;                                // m_local
        tile[row][tc] = emb[kidx[row] * 256 + ct * 32 + tc];  // coalesced along c
    }
    __syncthreads();
#pragma unroll
    for (int rr = 0; rr < 4; ++rr) {
        int cl = tr + rr * 8;                                 // c_local
        out[b * 524288 + (ct * 32 + cl) * 2048 + mt * 32 + tc] = tile[tc][cl];
    }
}

// ---------------- final loss reduce ----------------
__global__ void k_loss(const double* __restrict__ dmin, float* __restrict__ out) {
    __shared__ double sm[256];
    double s = 0.0;
    for (int i = threadIdx.x; i < NROWS; i += 256) s += dmin[i];
    sm[threadIdx.x] = s;
    __syncthreads();
    for (int o = 128; o; o >>= 1) {
        if (threadIdx.x < o) sm[threadIdx.x] += sm[threadIdx.x + o];
        __syncthreads();
    }
    if (threadIdx.x == 0)
        out[OUT_LOSS] = (float)(1.25 * sm[0] / 4194304.0);
}

// ---------------- launch ----------------
extern "C" void kernel_launch(void* const* d_in, const int* in_sizes, int n_in,
                              void* d_out, int out_size, void* d_ws, size_t ws_size,
                              hipStream_t stream) {
    const float* Z = (const float*)d_in[0];   // [8,256,8,16,16] fp32
    const float* E = (const float*)d_in[1];   // [8192,256] fp32
    float* out = (float*)d_out;
    char* ws = (char*)d_ws;

    float*  S1      = (float*)ws;                             // 64 KB
    float*  rowmin  = (float*)(ws + (64 << 10));              // 64 KB
    double* dmin    = (double*)(ws + (128 << 10));            // 128 KB
    int*    idxv    = (int*)(ws + (256 << 10));               // 64 KB
    float*  partmin = (float*)(ws + (320 << 10));             // 2 MB

    hipLaunchKernelGGL(k_s1,     dim3(64),   dim3(256), 0, stream, Z, S1);
    hipLaunchKernelGGL(k_screen, dim3(1024), dim3(256), 0, stream, Z, E, partmin);
    hipLaunchKernelGGL(k_rowmin, dim3(64),   dim3(256), 0, stream, partmin, rowmin);
    hipLaunchKernelGGL(k_rescue, dim3(4096), dim3(256), 0, stream, Z, E, S1,
                       partmin, rowmin, idxv, out);
    hipLaunchKernelGGL(k_dmin,   dim3(4096), dim3(256), 0, stream, Z, E, idxv, dmin);
    hipLaunchKernelGGL(k_gather, dim3(4096), dim3(256), 0, stream, E, idxv, out);
    hipLaunchKernelGGL(k_loss,   dim3(1),    dim3(256), 0, stream, dmin, out);
}

// Round 6
// 2283.593 us; speedup vs baseline: 7.6241x; 7.6241x over previous
//
#include <hip/hip_runtime.h>

// Problem constants
#define NROWS 16384      // 8 * (8*16*16)
#define NE 8192
#define NCH 64           // k-chunks per row (= k-tiles of the MFMA screen)
#define CHK 128          // k's per chunk
#define OUT_LOSS 4194304
#define OUT_IDX  4194305

#define U_MARGIN  2.5e-5f   // np-gap 1.55e-5 + screen err 2e-6 + slack
#define CH_MARGIN 3.0e-5f

typedef __attribute__((ext_vector_type(8))) short short8;
typedef __attribute__((ext_vector_type(8))) unsigned short u16x8;
typedef __attribute__((ext_vector_type(4))) float f32x4;

__device__ inline unsigned short bf16_rne(float f) {
    unsigned u = __float_as_uint(f);
    return (unsigned short)((u + 0x7FFFu + ((u >> 16) & 1u)) >> 16);
}

// ---------------- S1[n] = np.sum(zf*zf, axis=1) bit-exact emulation ----------------
__global__ void k_s1(const float* __restrict__ Z, float* __restrict__ S1) {
#pragma clang fp contract(off)
    const int n = blockIdx.x * 256 + threadIdx.x;
    const int b = n >> 11, m = n & 2047;
    const float* zp = Z + b * 524288 + m;
    float blk[2];
#pragma unroll
    for (int h = 0; h < 2; ++h) {
        float r[8];
#pragma unroll
        for (int j = 0; j < 8; ++j) {
            float z = zp[(h * 128 + j) * 2048];
            float w = z * z;
            asm("" : "+v"(w));
            r[j] = w;
        }
        for (int t2 = 1; t2 < 16; ++t2) {
#pragma unroll
            for (int j = 0; j < 8; ++j) {
                float z = zp[(h * 128 + t2 * 8 + j) * 2048];
                float w = z * z;
                asm("" : "+v"(w));
                r[j] += w;
            }
        }
        float s01 = r[0] + r[1], s23 = r[2] + r[3];
        float s45 = r[4] + r[5], s67 = r[6] + r[7];
        blk[h] = (s01 + s23) + (s45 + s67);
    }
    S1[n] = blk[0] + blk[1];
}

// ---------------- prep: Z -> Zt hi/lo bf16 [16384][256] (transposed) ----------------
__global__ void k_prep_z(const float* __restrict__ Z, unsigned short* __restrict__ Zh,
                         unsigned short* __restrict__ Zl) {
    __shared__ float tile[32][33];
    const int blk = blockIdx.x;          // b*512 + ct*64 + mt
    const int mt = blk & 63;
    const int ct = (blk >> 6) & 7;
    const int b  = blk >> 9;
    const int t = threadIdx.x, tr = t >> 5, tc = t & 31;
#pragma unroll
    for (int rr = 0; rr < 4; ++rr) {
        int cl = tr + rr * 8;
        tile[cl][tc] = Z[b * 524288 + (ct * 32 + cl) * 2048 + mt * 32 + tc]; // coalesced (m)
    }
    __syncthreads();
#pragma unroll
    for (int rr = 0; rr < 4; ++rr) {
        int nl = tr + rr * 8;                 // m_local
        float x = tile[tc][nl];
        unsigned short h = bf16_rne(x);
        float hf = __uint_as_float((unsigned)h << 16);
        unsigned short lo = bf16_rne(x - hf);
        int n = b * 2048 + mt * 32 + nl;
        Zh[n * 256 + ct * 32 + tc] = h;       // coalesced (c)
        Zl[n * 256 + ct * 32 + tc] = lo;
    }
}

// ---------------- prep: E -> hi/lo bf16 [8192][256] ----------------
__global__ void k_prep_e(const float* __restrict__ E, unsigned short* __restrict__ Eh,
                         unsigned short* __restrict__ El) {
    const int g = blockIdx.x * 256 + threadIdx.x;      // 524288 float4's
    float4 v = reinterpret_cast<const float4*>(E)[g];
    ushort4 h, lo;
    h.x = bf16_rne(v.x); h.y = bf16_rne(v.y); h.z = bf16_rne(v.z); h.w = bf16_rne(v.w);
    lo.x = bf16_rne(v.x - __uint_as_float((unsigned)h.x << 16));
    lo.y = bf16_rne(v.y - __uint_as_float((unsigned)h.y << 16));
    lo.z = bf16_rne(v.z - __uint_as_float((unsigned)h.z << 16));
    lo.w = bf16_rne(v.w - __uint_as_float((unsigned)h.w << 16));
    reinterpret_cast<ushort4*>(Eh)[g] = h;
    reinterpret_cast<ushort4*>(El)[g] = lo;
}

// ---------------- MFMA screen: partmin[kt][n] = min over 128 k of -(z.e) ----------------
// 128x128 output tile, BK=64, 4 waves (2x2). bf16 double-split: p = hh + hl + lh.
// LDS tiles [128][64] bf16 with T2 XOR-swizzle (byte ^= (row&7)<<4), reg-staged writes.
// Frag layout: A/B lane l -> row l&15, k = (l>>4)*8 + 0..7 (ds_read_b128);
// C/D: col = lane&15, row = (lane>>4)*4 + reg  [m89-verified].
#define SM_A_H 0
#define SM_A_L 16384
#define SM_B_H 32768
#define SM_B_L 49152
__launch_bounds__(256, 2)
__global__ void k_screen(const unsigned short* __restrict__ Zh, const unsigned short* __restrict__ Zl,
                         const unsigned short* __restrict__ Eh, const unsigned short* __restrict__ El,
                         float* __restrict__ partmin) {
    __shared__ __align__(16) char lds[65536];
    __shared__ float smin[2][128];
    const int t = threadIdx.x;
    const int nt = blockIdx.x >> 6;      // 128 n-tiles
    const int kt = blockIdx.x & 63;      // 64 k-tiles
    const int n0 = nt * 128, k0 = kt * 128;
    const int w = t >> 6, l = t & 63;
    const int wm = w >> 1, wn = w & 1;

    f32x4 acc[4][4];
#pragma unroll
    for (int i = 0; i < 4; ++i)
#pragma unroll
        for (int j = 0; j < 4; ++j) acc[i][j] = (f32x4)(0.0f);

    const int r = t >> 1;                // staging row 0..127
    const int gbase = (t & 1) * 4;       // 16B-granule base (8 per 128B row)

    for (int kb = 0; kb < 4; ++kb) {
        const int c0 = kb * 64;
        if (kb) __syncthreads();
#pragma unroll
        for (int i = 0; i < 4; ++i) {
            const int g16 = gbase + i;
            const int off = r * 128 + ((g16 << 4) ^ ((r & 7) << 4));
            const int ge = c0 + g16 * 8;  // elem offset within the 256-wide row
            *(u16x8*)(lds + SM_A_H + off) = *(const u16x8*)(Zh + (n0 + r) * 256 + ge);
            *(u16x8*)(lds + SM_A_L + off) = *(const u16x8*)(Zl + (n0 + r) * 256 + ge);
            *(u16x8*)(lds + SM_B_H + off) = *(const u16x8*)(Eh + (k0 + r) * 256 + ge);
            *(u16x8*)(lds + SM_B_L + off) = *(const u16x8*)(El + (k0 + r) * 256 + ge);
        }
        __syncthreads();
#pragma unroll
        for (int ks = 0; ks < 2; ++ks) {
            const int cb = ks * 64 + ((l >> 4) << 4);
            short8 ah[4], al[4], bh[4], bl[4];
#pragma unroll
            for (int mf = 0; mf < 4; ++mf) {
                const int ar = wm * 64 + mf * 16 + (l & 15);
                const int off = ar * 128 + (cb ^ ((ar & 7) << 4));
                ah[mf] = *(const short8*)(lds + SM_A_H + off);
                al[mf] = *(const short8*)(lds + SM_A_L + off);
            }
#pragma unroll
            for (int nf = 0; nf < 4; ++nf) {
                const int br = wn * 64 + nf * 16 + (l & 15);
                const int off = br * 128 + (cb ^ ((br & 7) << 4));
                bh[nf] = *(const short8*)(lds + SM_B_H + off);
                bl[nf] = *(const short8*)(lds + SM_B_L + off);
            }
#pragma unroll
            for (int mf = 0; mf < 4; ++mf)
#pragma unroll
                for (int nf = 0; nf < 4; ++nf) {
                    acc[mf][nf] = __builtin_amdgcn_mfma_f32_16x16x32_bf16(ah[mf], bh[nf], acc[mf][nf], 0, 0, 0);
                    acc[mf][nf] = __builtin_amdgcn_mfma_f32_16x16x32_bf16(ah[mf], bl[nf], acc[mf][nf], 0, 0, 0);
                    acc[mf][nf] = __builtin_amdgcn_mfma_f32_16x16x32_bf16(al[mf], bh[nf], acc[mf][nf], 0, 0, 0);
                }
        }
    }

    // epilogue: per-row min of u = -P over this block's 128 k's
#pragma unroll
    for (int mf = 0; mf < 4; ++mf) {
        float vr[4];
#pragma unroll
        for (int q = 0; q < 4; ++q) {
            float x = -acc[mf][0][q];
            x = fminf(x, -acc[mf][1][q]);
            x = fminf(x, -acc[mf][2][q]);
            x = fminf(x, -acc[mf][3][q]);
            vr[q] = x;
        }
#pragma unroll
        for (int o = 1; o < 16; o <<= 1) {
#pragma unroll
            for (int q = 0; q < 4; ++q) vr[q] = fminf(vr[q], __shfl_xor(vr[q], o));
        }
        if ((l & 15) == 0) {
            const int rowl = wm * 64 + mf * 16 + ((l >> 4) << 2);
#pragma unroll
            for (int q = 0; q < 4; ++q) smin[wn][rowl + q] = vr[q];
        }
    }
    __syncthreads();
    if (t < 128)
        partmin[kt * NROWS + n0 + t] = fminf(smin[0][t], smin[1][t]);
}

// ---------------- rowmin[n] = min over chunks ----------------
__global__ void k_rowmin(const float* __restrict__ partmin, float* __restrict__ rowmin) {
    const int n = blockIdx.x * 256 + threadIdx.x;
    float mn = INFINITY;
#pragma unroll
    for (int ch = 0; ch < NCH; ++ch) mn = fminf(mn, partmin[ch * NROWS + n]);
    rowmin[n] = mn;
}

// ---------------- rescue: exact np-emulation on candidates only ----------------
__global__ void k_rescue(const float* __restrict__ Z, const float* __restrict__ E,
                         const float* __restrict__ S1, const float* __restrict__ partmin,
                         const float* __restrict__ rowmin, int* __restrict__ idxv,
                         float* __restrict__ out) {
#pragma clang fp contract(off)
    __shared__ __align__(16) float zsm[4][256];
    const int t = threadIdx.x;
    const int r = t >> 6;            // wave id = row within block
    const int lane = t & 63;
    const int n = blockIdx.x * 4 + r;
    const int b = n >> 11, m = n & 2047;

#pragma unroll
    for (int i = 0; i < 4; ++i)
        zsm[r][lane + 64 * i] = Z[b * 524288 + (lane + 64 * i) * 2048 + m];
    __syncthreads();

    const float4* zf4 = reinterpret_cast<const float4*>(zsm[r]);
    const float rowm = rowmin[n];
    const float s1v = S1[n];

    unsigned long long best = 0xFFFFFFFFFFFFFFFFull;

    float pm = partmin[lane * NROWS + n];      // lane == chunk (NCH=64)
    unsigned long long qm = __ballot(pm <= rowm + CH_MARGIN);
    while (qm) {
        const int ch = __ffsll(qm) - 1;
        qm &= qm - 1;
        const int c0 = ch * CHK;
#pragma unroll 1
        for (int s = 0; s < 2; ++s) {
            const int k = c0 + s * 64 + lane;
            const float4* ef = reinterpret_cast<const float4*>(E + k * 256);
            float ax = 0.f, ay = 0.f, az = 0.f, aw = 0.f;
#pragma unroll
            for (int u = 0; u < 64; ++u) {
                float4 e4 = ef[u];
                float4 zz = zf4[u];
                ax = fmaf(zz.x, e4.x, ax);
                ay = fmaf(zz.y, e4.y, ay);
                az = fmaf(zz.z, e4.z, az);
                aw = fmaf(zz.w, e4.w, aw);
            }
            const float uk = -((ax + ay) + (az + aw));
            if (uk <= rowm + U_MARGIN) {
                // exact np SSE 4-chain emulation (sequential, no fma, no reassoc)
                float a0 = 0.f, a1 = 0.f, a2 = 0.f, a3 = 0.f;
#pragma unroll
                for (int u = 0; u < 64; ++u) {
                    float4 e4 = ef[u];
                    float4 zz = zf4[u];
                    float p0 = zz.x * e4.x; asm("" : "+v"(p0)); a0 += p0;
                    float p1 = zz.y * e4.y; asm("" : "+v"(p1)); a1 += p1;
                    float p2 = zz.z * e4.z; asm("" : "+v"(p2)); a2 += p2;
                    float p3 = zz.w * e4.w; asm("" : "+v"(p3)); a3 += p3;
                }
                float t1 = a0 + a1;
                float t2 = a2 + a3;
                float Pn = t1 + t2;                 // fl(fl(A0+A1)+fl(A2+A3))
                float d = s1v - 2.0f * Pn;          // fl(S1 - 2P), S2 absorbed
                unsigned long long pk =
                    ((unsigned long long)__float_as_uint(d) << 32) | (unsigned)k;
                if (pk < best) best = pk;
            }
        }
    }

#pragma unroll
    for (int o = 32; o; o >>= 1) {
        unsigned lo = (unsigned)(best & 0xFFFFFFFFull);
        unsigned hi = (unsigned)(best >> 32);
        unsigned olo = __shfl_xor(lo, o);
        unsigned ohi = __shfl_xor(hi, o);
        unsigned long long ob = ((unsigned long long)ohi << 32) | olo;
        if (ob < best) best = ob;
    }
    if (lane == 0) {
        const int bi = (int)(best & 0xFFFFFFFFull);
        idxv[n] = bi;
        out[OUT_IDX + n] = (float)bi;
    }
}

// ---------------- fp64 ||z - e_idx||^2 per row (for the loss) ----------------
__global__ void k_dmin(const float* __restrict__ Z, const float* __restrict__ E,
                       const int* __restrict__ idxv, double* __restrict__ dmin) {
    const int n = blockIdx.x * 4 + (threadIdx.x >> 6);
    const int lane = threadIdx.x & 63;
    const int b = n >> 11, m = n & 2047;
    const int kk = idxv[n];
    const float4 e4 = reinterpret_cast<const float4*>(E + kk * 256)[lane];
    const float* zp = Z + b * 524288 + m;
    double d0 = (double)zp[(4 * lane + 0) * 2048] - (double)e4.x;
    double d1 = (double)zp[(4 * lane + 1) * 2048] - (double)e4.y;
    double d2 = (double)zp[(4 * lane + 2) * 2048] - (double)e4.z;
    double d3 = (double)zp[(4 * lane + 3) * 2048] - (double)e4.w;
    double d = d0 * d0 + d1 * d1 + d2 * d2 + d3 * d3;
    for (int o = 32; o; o >>= 1) d += __shfl_xor(d, o);
    if (lane == 0) dmin[n] = d;
}

// ---------------- gather z_q with LDS transpose ----------------
__global__ void k_gather(const float* __restrict__ emb, const int* __restrict__ idxv,
                         float* __restrict__ out) {
    __shared__ float tile[32][33];
    __shared__ int kidx[32];
    const int blk = blockIdx.x;
    const int ct = blk & 7;
    const int mt = (blk >> 3) & 63;
    const int b = blk >> 9;
    const int t = threadIdx.x, tr = t >> 5, tc = t & 31;

    if (t < 32) kidx[t] = idxv[b * 2048 + mt * 32 + t];
    __syncthreads();
#pragma unroll
    for (int rr = 0; rr < 4; ++rr) {
        int row = tr + rr * 8;
        tile[row][tc] = emb[kidx[row] * 256 + ct * 32 + tc];
    }
    __syncthreads();
#pragma unroll
    for (int rr = 0; rr < 4; ++rr) {
        int cl = tr + rr * 8;
        out[b * 524288 + (ct * 32 + cl) * 2048 + mt * 32 + tc] = tile[tc][cl];
    }
}

// ---------------- final loss reduce ----------------
__global__ void k_loss(const double* __restrict__ dmin, float* __restrict__ out) {
    __shared__ double sm[256];
    double s = 0.0;
    for (int i = threadIdx.x; i < NROWS; i += 256) s += dmin[i];
    sm[threadIdx.x] = s;
    __syncthreads();
    for (int o = 128; o; o >>= 1) {
        if (threadIdx.x < o) sm[threadIdx.x] += sm[threadIdx.x + o];
        __syncthreads();
    }
    if (threadIdx.x == 0)
        out[OUT_LOSS] = (float)(1.25 * sm[0] / 4194304.0);
}

// ---------------- launch ----------------
extern "C" void kernel_launch(void* const* d_in, const int* in_sizes, int n_in,
                              void* d_out, int out_size, void* d_ws, size_t ws_size,
                              hipStream_t stream) {
    const float* Z = (const float*)d_in[0];   // [8,256,8,16,16] fp32
    const float* E = (const float*)d_in[1];   // [8192,256] fp32
    float* out = (float*)d_out;
    char* ws = (char*)d_ws;

    size_t o = 0;
    float*  S1      = (float*)(ws + o);  o += 64 << 10;
    float*  rowmin  = (float*)(ws + o);  o += 64 << 10;
    double* dmin    = (double*)(ws + o); o += 128 << 10;
    int*    idxv    = (int*)(ws + o);    o += 64 << 10;
    float*  partmin = (float*)(ws + o);  o += (size_t)NCH * NROWS * 4;      // 4 MB
    unsigned short* Zh = (unsigned short*)(ws + o); o += (size_t)NROWS * 256 * 2;  // 8 MB
    unsigned short* Zl = (unsigned short*)(ws + o); o += (size_t)NROWS * 256 * 2;  // 8 MB
    unsigned short* Eh = (unsigned short*)(ws + o); o += (size_t)NE * 256 * 2;     // 4 MB
    unsigned short* El = (unsigned short*)(ws + o); o += (size_t)NE * 256 * 2;     // 4 MB

    hipLaunchKernelGGL(k_prep_z, dim3(4096), dim3(256), 0, stream, Z, Zh, Zl);
    hipLaunchKernelGGL(k_prep_e, dim3(2048), dim3(256), 0, stream, E, Eh, El);
    hipLaunchKernelGGL(k_s1,     dim3(64),   dim3(256), 0, stream, Z, S1);
    hipLaunchKernelGGL(k_screen, dim3(8192), dim3(256), 0, stream, Zh, Zl, Eh, El, partmin);
    hipLaunchKernelGGL(k_rowmin, dim3(64),   dim3(256), 0, stream, partmin, rowmin);
    hipLaunchKernelGGL(k_rescue, dim3(4096), dim3(256), 0, stream, Z, E, S1,
                       partmin, rowmin, idxv, out);
    hipLaunchKernelGGL(k_dmin,   dim3(4096), dim3(256), 0, stream, Z, E, idxv, dmin);
    hipLaunchKernelGGL(k_gather, dim3(4096), dim3(256), 0, stream, E, idxv, out);
    hipLaunchKernelGGL(k_loss,   dim3(1),    dim3(256), 0, stream, dmin, out);
}

// Round 7
// 572.218 us; speedup vs baseline: 30.4259x; 3.9908x over previous
//
#include <hip/hip_runtime.h>

// Problem constants
#define NROWS 16384      // 8 * (8*16*16)
#define NE 8192
#define NCH 64           // k-chunks per row (= k-tiles of the MFMA screen)
#define CHK 128          // k's per chunk
#define OUT_LOSS 4194304
#define OUT_IDX  4194305

#define U_MARGIN  2.5e-5f   // np-gap 1.55e-5 + screen err 2e-6 + slack
#define CH_MARGIN 3.0e-5f

typedef __attribute__((ext_vector_type(8))) short short8;
typedef __attribute__((ext_vector_type(8))) unsigned short u16x8;
typedef __attribute__((ext_vector_type(4))) float f32x4;

__device__ inline unsigned short bf16_rne(float f) {
    unsigned u = __float_as_uint(f);
    return (unsigned short)((u + 0x7FFFu + ((u >> 16) & 1u)) >> 16);
}

// exact np SSE 4-chain emulation of fl(S1 - 2*P) (sequential, no fma, no reassoc)
__device__ inline float np_dist(const float4* __restrict__ zf4,
                                const float4* __restrict__ ef, float s1v) {
#pragma clang fp contract(off)
    float a0 = 0.f, a1 = 0.f, a2 = 0.f, a3 = 0.f;
#pragma unroll
    for (int u = 0; u < 64; ++u) {
        float4 e4 = ef[u];
        float4 zz = zf4[u];
        float p0 = zz.x * e4.x; asm("" : "+v"(p0)); a0 += p0;
        float p1 = zz.y * e4.y; asm("" : "+v"(p1)); a1 += p1;
        float p2 = zz.z * e4.z; asm("" : "+v"(p2)); a2 += p2;
        float p3 = zz.w * e4.w; asm("" : "+v"(p3)); a3 += p3;
    }
    float t1 = a0 + a1;
    float t2 = a2 + a3;
    float Pn = t1 + t2;                 // fl(fl(A0+A1)+fl(A2+A3))
    return s1v - 2.0f * Pn;             // fl(S1 - 2P), S2 absorbed
}

// ---------------- S1[n] = np.sum(zf*zf, axis=1) bit-exact emulation ----------------
__global__ void k_s1(const float* __restrict__ Z, float* __restrict__ S1) {
#pragma clang fp contract(off)
    const int n = blockIdx.x * 256 + threadIdx.x;
    const int b = n >> 11, m = n & 2047;
    const float* zp = Z + b * 524288 + m;
    float blk[2];
#pragma unroll
    for (int h = 0; h < 2; ++h) {
        float r[8];
#pragma unroll
        for (int j = 0; j < 8; ++j) {
            float z = zp[(h * 128 + j) * 2048];
            float w = z * z;
            asm("" : "+v"(w));
            r[j] = w;
        }
        for (int t2 = 1; t2 < 16; ++t2) {
#pragma unroll
            for (int j = 0; j < 8; ++j) {
                float z = zp[(h * 128 + t2 * 8 + j) * 2048];
                float w = z * z;
                asm("" : "+v"(w));
                r[j] += w;
            }
        }
        float s01 = r[0] + r[1], s23 = r[2] + r[3];
        float s45 = r[4] + r[5], s67 = r[6] + r[7];
        blk[h] = (s01 + s23) + (s45 + s67);
    }
    S1[n] = blk[0] + blk[1];
}

// ---------------- prep: Z -> Zt fp32 + hi/lo bf16 [16384][256] (transposed) ----------------
__global__ void k_prep_z(const float* __restrict__ Z, float* __restrict__ Zt,
                         unsigned short* __restrict__ Zh, unsigned short* __restrict__ Zl) {
    __shared__ float tile[32][33];
    const int blk = blockIdx.x;          // b*512 + ct*64 + mt
    const int mt = blk & 63;
    const int ct = (blk >> 6) & 7;
    const int b  = blk >> 9;
    const int t = threadIdx.x, tr = t >> 5, tc = t & 31;
#pragma unroll
    for (int rr = 0; rr < 4; ++rr) {
        int cl = tr + rr * 8;
        tile[cl][tc] = Z[b * 524288 + (ct * 32 + cl) * 2048 + mt * 32 + tc]; // coalesced (m)
    }
    __syncthreads();
#pragma unroll
    for (int rr = 0; rr < 4; ++rr) {
        int nl = tr + rr * 8;                 // m_local
        float x = tile[tc][nl];
        unsigned short h = bf16_rne(x);
        float hf = __uint_as_float((unsigned)h << 16);
        unsigned short lo = bf16_rne(x - hf);
        int n = b * 2048 + mt * 32 + nl;
        Zt[n * 256 + ct * 32 + tc] = x;       // coalesced (c)
        Zh[n * 256 + ct * 32 + tc] = h;
        Zl[n * 256 + ct * 32 + tc] = lo;
    }
}

// ---------------- prep: E -> hi/lo bf16 [8192][256] ----------------
__global__ void k_prep_e(const float* __restrict__ E, unsigned short* __restrict__ Eh,
                         unsigned short* __restrict__ El) {
    const int g = blockIdx.x * 256 + threadIdx.x;      // 524288 float4's
    float4 v = reinterpret_cast<const float4*>(E)[g];
    ushort4 h, lo;
    h.x = bf16_rne(v.x); h.y = bf16_rne(v.y); h.z = bf16_rne(v.z); h.w = bf16_rne(v.w);
    lo.x = bf16_rne(v.x - __uint_as_float((unsigned)h.x << 16));
    lo.y = bf16_rne(v.y - __uint_as_float((unsigned)h.y << 16));
    lo.z = bf16_rne(v.z - __uint_as_float((unsigned)h.z << 16));
    lo.w = bf16_rne(v.w - __uint_as_float((unsigned)h.w << 16));
    reinterpret_cast<ushort4*>(Eh)[g] = h;
    reinterpret_cast<ushort4*>(El)[g] = lo;
}

// ---------------- MFMA screen: partrec[n][kt] = (m1, m2, argmin-k) over 128 k's ----------------
// 128x128 output tile, BK=64, 4 waves (2x2). bf16 double-split: p = hh + hl + lh.
// LDS tiles [128][64] bf16 with XOR-swizzle (byte ^= (row&7)<<4), reg-staged writes.
// Frag layout: A/B lane l -> row l&15, k = (l>>4)*8 + 0..7 (ds_read_b128);
// C/D: col = lane&15, row = (lane>>4)*4 + reg  [m89-verified].
#define SM_A_H 0
#define SM_A_L 16384
#define SM_B_H 32768
#define SM_B_L 49152
__launch_bounds__(256, 2)
__global__ void k_screen(const unsigned short* __restrict__ Zh, const unsigned short* __restrict__ Zl,
                         const unsigned short* __restrict__ Eh, const unsigned short* __restrict__ El,
                         float4* __restrict__ partrec) {
    __shared__ __align__(16) char lds[65536];
    __shared__ float sm1[2][128];
    __shared__ float sm2[2][128];
    __shared__ int   sk1[2][128];
    const int t = threadIdx.x;
    const int nt = blockIdx.x >> 6;      // 128 n-tiles
    const int kt = blockIdx.x & 63;      // 64 k-tiles
    const int n0 = nt * 128, k0 = kt * 128;
    const int w = t >> 6, l = t & 63;
    const int wm = w >> 1, wn = w & 1;

    f32x4 acc[4][4];
#pragma unroll
    for (int i = 0; i < 4; ++i)
#pragma unroll
        for (int j = 0; j < 4; ++j) acc[i][j] = (f32x4)(0.0f);

    const int r = t >> 1;                // staging row 0..127
    const int gbase = (t & 1) * 4;       // 16B-granule base (8 per 128B row)

    for (int kb = 0; kb < 4; ++kb) {
        const int c0 = kb * 64;
        if (kb) __syncthreads();
#pragma unroll
        for (int i = 0; i < 4; ++i) {
            const int g16 = gbase + i;
            const int off = r * 128 + ((g16 << 4) ^ ((r & 7) << 4));
            const int ge = c0 + g16 * 8;  // elem offset within the 256-wide row
            *(u16x8*)(lds + SM_A_H + off) = *(const u16x8*)(Zh + (n0 + r) * 256 + ge);
            *(u16x8*)(lds + SM_A_L + off) = *(const u16x8*)(Zl + (n0 + r) * 256 + ge);
            *(u16x8*)(lds + SM_B_H + off) = *(const u16x8*)(Eh + (k0 + r) * 256 + ge);
            *(u16x8*)(lds + SM_B_L + off) = *(const u16x8*)(El + (k0 + r) * 256 + ge);
        }
        __syncthreads();
#pragma unroll
        for (int ks = 0; ks < 2; ++ks) {
            const int cb = ks * 64 + ((l >> 4) << 4);
            short8 ah[4], al[4], bh[4], bl[4];
#pragma unroll
            for (int mf = 0; mf < 4; ++mf) {
                const int ar = wm * 64 + mf * 16 + (l & 15);
                const int off = ar * 128 + (cb ^ ((ar & 7) << 4));
                ah[mf] = *(const short8*)(lds + SM_A_H + off);
                al[mf] = *(const short8*)(lds + SM_A_L + off);
            }
#pragma unroll
            for (int nf = 0; nf < 4; ++nf) {
                const int br = wn * 64 + nf * 16 + (l & 15);
                const int off = br * 128 + (cb ^ ((br & 7) << 4));
                bh[nf] = *(const short8*)(lds + SM_B_H + off);
                bl[nf] = *(const short8*)(lds + SM_B_L + off);
            }
#pragma unroll
            for (int mf = 0; mf < 4; ++mf)
#pragma unroll
                for (int nf = 0; nf < 4; ++nf) {
                    acc[mf][nf] = __builtin_amdgcn_mfma_f32_16x16x32_bf16(ah[mf], bh[nf], acc[mf][nf], 0, 0, 0);
                    acc[mf][nf] = __builtin_amdgcn_mfma_f32_16x16x32_bf16(ah[mf], bl[nf], acc[mf][nf], 0, 0, 0);
                    acc[mf][nf] = __builtin_amdgcn_mfma_f32_16x16x32_bf16(al[mf], bh[nf], acc[mf][nf], 0, 0, 0);
                }
        }
    }

    // epilogue: per-row top-2 + argmin of u = -P over this tile's 128 k's
#pragma unroll
    for (int mf = 0; mf < 4; ++mf) {
#pragma unroll
        for (int q = 0; q < 4; ++q) {
            float m1 = -acc[mf][0][q];
            int kk1 = wn * 64 + (l & 15);
            float m2 = INFINITY;
#pragma unroll
            for (int nf = 1; nf < 4; ++nf) {
                float v = -acc[mf][nf][q];
                int c = wn * 64 + nf * 16 + (l & 15);
                if (v < m1) { m2 = m1; m1 = v; kk1 = c; }
                else m2 = fminf(m2, v);
            }
#pragma unroll
            for (int o = 1; o < 16; o <<= 1) {
                float om1 = __shfl_xor(m1, o);
                float om2 = __shfl_xor(m2, o);
                int   ok  = __shfl_xor(kk1, o);
                float hi = fmaxf(m1, om1);
                if (om1 < m1) { kk1 = ok; m1 = om1; }
                m2 = fminf(fminf(m2, om2), hi);
            }
            if ((l & 15) == 0) {
                const int rowl = wm * 64 + mf * 16 + ((l >> 4) << 2) + q;
                sm1[wn][rowl] = m1; sm2[wn][rowl] = m2; sk1[wn][rowl] = kk1;
            }
        }
    }
    __syncthreads();
    if (t < 128) {
        float a1 = sm1[0][t], a2 = sm2[0][t]; int ak = sk1[0][t];
        float b1 = sm1[1][t], b2 = sm2[1][t]; int bk = sk1[1][t];
        float hi = fmaxf(a1, b1);
        float m1 = a1; int kk = ak;
        if (b1 < a1) { m1 = b1; kk = bk; }
        float m2 = fminf(fminf(a2, b2), hi);
        partrec[(size_t)(n0 + t) * NCH + kt] =
            make_float4(m1, m2, __int_as_float(k0 + kk), 0.0f);
    }
}

// ---------------- rescue: exact np-emulation on nominated candidates ----------------
// one wave per row. Path A: chunk-argmin candidates (typ. ~1/row). Path B: rare
// fallback full-chunk re-screen when a chunk's 2nd-min is also within margin.
// Also computes fp64 ||z - e_best||^2 for the loss (folds old k_dmin).
__global__ void k_rescue(const float* __restrict__ Zt, const float* __restrict__ E,
                         const float* __restrict__ S1, const float4* __restrict__ partrec,
                         int* __restrict__ idxv, double* __restrict__ dmin,
                         float* __restrict__ out) {
#pragma clang fp contract(off)
    __shared__ __align__(16) float zsm[4][256];
    const int t = threadIdx.x;
    const int r = t >> 6;            // wave id = row within block
    const int lane = t & 63;
    const int n = blockIdx.x * 4 + r;

    // stage z row (coalesced float4 from transposed Zt)
    reinterpret_cast<float4*>(zsm[r])[lane] =
        reinterpret_cast<const float4*>(Zt)[(size_t)n * 64 + lane];
    __syncthreads();

    const float4* zf4 = reinterpret_cast<const float4*>(zsm[r]);
    const float s1v = S1[n];

    float4 rec = partrec[(size_t)n * NCH + lane];     // lane == chunk
    float pm1 = rec.x, pm2 = rec.y;
    int pk = __float_as_int(rec.z);

    float rowm = pm1;
#pragma unroll
    for (int o = 1; o < 64; o <<= 1) rowm = fminf(rowm, __shfl_xor(rowm, o));

    unsigned long long best = 0xFFFFFFFFFFFFFFFFull;

    // Path A: emulate this chunk's argmin if within margin
    if (pm1 <= rowm + U_MARGIN) {
        const float4* ef = reinterpret_cast<const float4*>(E + (size_t)pk * 256);
        float d = np_dist(zf4, ef, s1v);
        best = ((unsigned long long)__float_as_uint(d) << 32) | (unsigned)pk;
    }

    // Path B: full re-screen of chunks whose 2nd-min is also within margin
    unsigned long long qm = __ballot(pm2 <= rowm + CH_MARGIN);
    while (qm) {
        const int ch = __ffsll(qm) - 1;
        qm &= qm - 1;
        const int c0 = ch * CHK;
#pragma unroll 1
        for (int s = 0; s < 2; ++s) {
            const int k = c0 + s * 64 + lane;
            const float4* ef = reinterpret_cast<const float4*>(E + (size_t)k * 256);
            float ax = 0.f, ay = 0.f, az = 0.f, aw = 0.f;
#pragma unroll
            for (int u = 0; u < 64; ++u) {
                float4 e4 = ef[u];
                float4 zz = zf4[u];
                ax = fmaf(zz.x, e4.x, ax);
                ay = fmaf(zz.y, e4.y, ay);
                az = fmaf(zz.z, e4.z, az);
                aw = fmaf(zz.w, e4.w, aw);
            }
            const float uk = -((ax + ay) + (az + aw));
            if (uk <= rowm + U_MARGIN) {
                float d = np_dist(zf4, ef, s1v);
                unsigned long long pkd =
                    ((unsigned long long)__float_as_uint(d) << 32) | (unsigned)k;
                if (pkd < best) best = pkd;
            }
        }
    }

    // wave-reduce lexicographic min of (d, k)
#pragma unroll
    for (int o = 32; o; o >>= 1) {
        unsigned lo = (unsigned)(best & 0xFFFFFFFFull);
        unsigned hi = (unsigned)(best >> 32);
        unsigned olo = __shfl_xor(lo, o);
        unsigned ohi = __shfl_xor(hi, o);
        unsigned long long ob = ((unsigned long long)ohi << 32) | olo;
        if (ob < best) best = ob;
    }
    const int besti = (int)(best & 0xFFFFFFFFull);

    // fp64 ||z - e_best||^2 (for the loss)
    {
        float4 e4 = reinterpret_cast<const float4*>(E + (size_t)besti * 256)[lane];
        float4 zz = zf4[lane];
        double d0 = (double)zz.x - (double)e4.x;
        double d1 = (double)zz.y - (double)e4.y;
        double d2 = (double)zz.z - (double)e4.z;
        double d3 = (double)zz.w - (double)e4.w;
        double d = d0 * d0 + d1 * d1 + d2 * d2 + d3 * d3;
#pragma unroll
        for (int o = 32; o; o >>= 1) d += __shfl_xor(d, o);
        if (lane == 0) {
            idxv[n] = besti;
            out[OUT_IDX + n] = (float)besti;
            dmin[n] = d;
        }
    }
}

// ---------------- gather z_q with LDS transpose ----------------
__global__ void k_gather(const float* __restrict__ emb, const int* __restrict__ idxv,
                         float* __restrict__ out) {
    __shared__ float tile[32][33];
    __shared__ int kidx[32];
    const int blk = blockIdx.x;
    const int ct = blk & 7;
    const int mt = (blk >> 3) & 63;
    const int b = blk >> 9;
    const int t = threadIdx.x, tr = t >> 5, tc = t & 31;

    if (t < 32) kidx[t] = idxv[b * 2048 + mt * 32 + t];
    __syncthreads();
#pragma unroll
    for (int rr = 0; rr < 4; ++rr) {
        int row = tr + rr * 8;
        tile[row][tc] = emb[kidx[row] * 256 + ct * 32 + tc];
    }
    __syncthreads();
#pragma unroll
    for (int rr = 0; rr < 4; ++rr) {
        int cl = tr + rr * 8;
        out[b * 524288 + (ct * 32 + cl) * 2048 + mt * 32 + tc] = tile[tc][cl];
    }
}

// ---------------- final loss reduce ----------------
__global__ void k_loss(const double* __restrict__ dmin, float* __restrict__ out) {
    __shared__ double sm[256];
    double s = 0.0;
    for (int i = threadIdx.x; i < NROWS; i += 256) s += dmin[i];
    sm[threadIdx.x] = s;
    __syncthreads();
    for (int o = 128; o; o >>= 1) {
        if (threadIdx.x < o) sm[threadIdx.x] += sm[threadIdx.x + o];
        __syncthreads();
    }
    if (threadIdx.x == 0)
        out[OUT_LOSS] = (float)(1.25 * sm[0] / 4194304.0);
}

// ---------------- launch ----------------
extern "C" void kernel_launch(void* const* d_in, const int* in_sizes, int n_in,
                              void* d_out, int out_size, void* d_ws, size_t ws_size,
                              hipStream_t stream) {
    const float* Z = (const float*)d_in[0];   // [8,256,8,16,16] fp32
    const float* E = (const float*)d_in[1];   // [8192,256] fp32
    float* out = (float*)d_out;
    char* ws = (char*)d_ws;

    size_t o = 0;
    float*  S1      = (float*)(ws + o);  o += 64 << 10;
    double* dmin    = (double*)(ws + o); o += 128 << 10;
    int*    idxv    = (int*)(ws + o);    o += 64 << 10;
    float4* partrec = (float4*)(ws + o); o += (size_t)NROWS * NCH * 16;            // 16 MB
    float*  Zt      = (float*)(ws + o);  o += (size_t)NROWS * 256 * 4;             // 16 MB
    unsigned short* Zh = (unsigned short*)(ws + o); o += (size_t)NROWS * 256 * 2;  // 8 MB
    unsigned short* Zl = (unsigned short*)(ws + o); o += (size_t)NROWS * 256 * 2;  // 8 MB
    unsigned short* Eh = (unsigned short*)(ws + o); o += (size_t)NE * 256 * 2;     // 4 MB
    unsigned short* El = (unsigned short*)(ws + o); o += (size_t)NE * 256 * 2;     // 4 MB

    hipLaunchKernelGGL(k_prep_z, dim3(4096), dim3(256), 0, stream, Z, Zt, Zh, Zl);
    hipLaunchKernelGGL(k_prep_e, dim3(2048), dim3(256), 0, stream, E, Eh, El);
    hipLaunchKernelGGL(k_s1,     dim3(64),   dim3(256), 0, stream, Z, S1);
    hipLaunchKernelGGL(k_screen, dim3(8192), dim3(256), 0, stream, Zh, Zl, Eh, El, partrec);
    hipLaunchKernelGGL(k_rescue, dim3(4096), dim3(256), 0, stream, Zt, E, S1,
                       partrec, idxv, dmin, out);
    hipLaunchKernelGGL(k_gather, dim3(4096), dim3(256), 0, stream, E, idxv, out);
    hipLaunchKernelGGL(k_loss,   dim3(1),    dim3(256), 0, stream, dmin, out);
}